// Round 3
// baseline (62.029 us; speedup 1.0000x reference)
//
#include <hip/hip_runtime.h>

// Problem constants (B=4, S=4096, DM=1024, H=16, HD=64)
#define M_TOTAL 16384
#define DMODEL  1024
#define HDIM    64
#define NHEAD   16

typedef _Float16 half8 __attribute__((ext_vector_type(8)));
typedef float    f32x4 __attribute__((ext_vector_type(4)));

// ---------------------------------------------------------------------------
// Math note: scores[b,s,h,g] = q.k is constant over g (k is broadcast over the
// head axis) -> softmax exactly uniform -> out rows = v -> final =
// (x@Wv+bv) @ (sum_h Wo[h*64+d][n]) + bo.  Wq/bq/Wk/bk are mathematically dead.
//
// Prep: WvT[d][k] = Wv[k][d]  (f16)          [64][1024]
//       WosumT[n][d] = sum_h Wo[h*64+d][n]   [1024][64] (f16)
// ---------------------------------------------------------------------------
__global__ __launch_bounds__(256) void prep_kernel(const float* __restrict__ Wv,
                                                   const float* __restrict__ Wo,
                                                   _Float16* __restrict__ WvT,
                                                   _Float16* __restrict__ WosumT) {
    const int t = blockIdx.x * 256 + threadIdx.x;   // 0..65535
    {   // WvT: consecutive t -> consecutive d -> coalesced Wv reads
        const int d = t & 63, k = t >> 6;
        WvT[d * DMODEL + k] = (_Float16)Wv[k * HDIM + d];
    }
    {   // WosumT: consecutive t -> consecutive n -> coalesced Wo reads
        const int n = t & 1023, d = t >> 10;
        float s = 0.f;
        #pragma unroll
        for (int h = 0; h < NHEAD; ++h) s += Wo[(h * HDIM + d) * DMODEL + n];
        WosumT[n * HDIM + d] = (_Float16)s;
    }
}

// ---------------------------------------------------------------------------
// Kernel A: V[16384][64] (f16) = X @ Wv + bv.
// Barrier-free: each wave owns 16 rows, full K=1024, all 64 output cols.
// X read direct global->reg with 4-step rotating prefetch (8 loads in flight).
// MFMA 16x16x32 f16: A lane l: A[l&15][(l>>4)*8+j]; B lane l: B[(l>>4)*8+j][l&15];
// C lane l reg j: row (l>>4)*4+j, col l&15.
// ---------------------------------------------------------------------------
__global__ __launch_bounds__(256) void vproj_kernel(const float* __restrict__ X,
                                                    const float* __restrict__ bv,
                                                    const _Float16* __restrict__ WvT,
                                                    _Float16* __restrict__ V) {
    const int tid = threadIdx.x;
    const int l   = tid & 63;
    const int w   = tid >> 6;
    const int lr  = l & 15;
    const int lk  = l >> 4;
    const int m0  = (blockIdx.x * 4 + w) * 16;      // wave-private 16 rows

    const float* xrow = X + (size_t)(m0 + lr) * DMODEL + lk * 8;

    f32x4 acc[4] = {};                              // cols n4*16+lr, rows lk*4+j
    float4 abuf[4][2];
    #pragma unroll
    for (int s = 0; s < 4; ++s) {
        abuf[s][0] = *(const float4*)(xrow + s * 32);
        abuf[s][1] = *(const float4*)(xrow + s * 32 + 4);
    }
    #pragma unroll 4
    for (int s = 0; s < 32; ++s) {
        const int slot = s & 3;                     // static under unroll-4
        const float4 x0 = abuf[slot][0];
        const float4 x1 = abuf[slot][1];
        if (s < 28) {
            abuf[slot][0] = *(const float4*)(xrow + (s + 4) * 32);
            abuf[slot][1] = *(const float4*)(xrow + (s + 4) * 32 + 4);
        }
        union { _Float16 h[8]; half8 v; } pk;
        pk.h[0] = (_Float16)x0.x; pk.h[1] = (_Float16)x0.y;
        pk.h[2] = (_Float16)x0.z; pk.h[3] = (_Float16)x0.w;
        pk.h[4] = (_Float16)x1.x; pk.h[5] = (_Float16)x1.y;
        pk.h[6] = (_Float16)x1.z; pk.h[7] = (_Float16)x1.w;
        #pragma unroll
        for (int n4 = 0; n4 < 4; ++n4) {
            const half8 b = *(const half8*)&WvT[(size_t)(n4 * 16 + lr) * DMODEL + s * 32 + lk * 8];
            acc[n4] = __builtin_amdgcn_mfma_f32_16x16x32_f16(pk.v, b, acc[n4], 0, 0, 0);
        }
    }
    #pragma unroll
    for (int n4 = 0; n4 < 4; ++n4) {
        const float bvv = bv[n4 * 16 + lr];
        #pragma unroll
        for (int j = 0; j < 4; ++j)
            V[(size_t)(m0 + lk * 4 + j) * HDIM + n4 * 16 + lr] = (_Float16)(acc[n4][j] + bvv);
    }
}

// ---------------------------------------------------------------------------
// Kernel B: Out[16384][1024] (f32) = V @ Wosum + bo.
// Barrier-free, no LDS: block = 16 rows; wave w owns cols [w*256,(w+1)*256).
// V (2 MB, L2-hot) read 16B/lane; WosumT (128 KB, L2-resident) streamed.
// ---------------------------------------------------------------------------
__global__ __launch_bounds__(256) void oproj_kernel(const _Float16* __restrict__ V,
                                                    const float* __restrict__ bo,
                                                    const _Float16* __restrict__ WosumT,
                                                    float* __restrict__ Out) {
    const int tid = threadIdx.x;
    const int l   = tid & 63;
    const int w   = tid >> 6;
    const int lr  = l & 15;
    const int lk  = l >> 4;
    const int m0  = blockIdx.x * 16;

    const _Float16* vp = V + (size_t)(m0 + lr) * HDIM + lk * 8;
    const half8 a0 = *(const half8*)vp;
    const half8 a1 = *(const half8*)(vp + 32);

    #pragma unroll 4
    for (int nf = 0; nf < 16; ++nf) {
        const int n0 = w * 256 + nf * 16;
        const half8 b0 = *(const half8*)&WosumT[(size_t)(n0 + lr) * HDIM + lk * 8];
        const half8 b1 = *(const half8*)&WosumT[(size_t)(n0 + lr) * HDIM + 32 + lk * 8];
        f32x4 o = {};
        o = __builtin_amdgcn_mfma_f32_16x16x32_f16(a0, b0, o, 0, 0, 0);
        o = __builtin_amdgcn_mfma_f32_16x16x32_f16(a1, b1, o, 0, 0, 0);
        const float bov = bo[n0 + lr];
        #pragma unroll
        for (int j = 0; j < 4; ++j)
            Out[(size_t)(m0 + lk * 4 + j) * DMODEL + n0 + lr] = o[j] + bov;
    }
}

// ---------------------------------------------------------------------------
extern "C" void kernel_launch(void* const* d_in, const int* in_sizes, int n_in,
                              void* d_out, int out_size, void* d_ws, size_t ws_size,
                              hipStream_t stream) {
    const float* x  = (const float*)d_in[0];
    // d_in[1]=Wq, d_in[2]=bq, d_in[3]=Wk, d_in[4]=bk: mathematically dead.
    const float* Wv = (const float*)d_in[5];
    const float* bv = (const float*)d_in[6];
    const float* Wo = (const float*)d_in[7];
    const float* bo = (const float*)d_in[8];

    _Float16* WvT    = (_Float16*)d_ws;                            // 128 KB
    _Float16* WosumT = (_Float16*)((char*)d_ws + 64 * 1024 * 2);   // 128 KB
    _Float16* V      = (_Float16*)((char*)d_ws + 256 * 1024);      // 2 MB (f16)
    float*    out    = (float*)d_out;

    prep_kernel<<<256, 256, 0, stream>>>(Wv, Wo, WvT, WosumT);
    vproj_kernel<<<M_TOTAL / 64, 256, 0, stream>>>(x, bv, WvT, V);
    oproj_kernel<<<M_TOTAL / 16, 256, 0, stream>>>(V, bo, WosumT, out);
}

// Round 4
// 53.317 us; speedup vs baseline: 1.1634x; 1.1634x over previous
//
#include <hip/hip_runtime.h>

// Problem constants (B=4, S=4096, DM=1024, H=16, HD=64)
#define M_TOTAL 16384
#define DMODEL  1024
#define HDIM    64
#define NHEAD   16

typedef _Float16 half8 __attribute__((ext_vector_type(8)));
typedef float    f32x4 __attribute__((ext_vector_type(4)));

// ---------------------------------------------------------------------------
// Math note: scores[b,s,h,g] = q.k is constant over g (k is broadcast over the
// head axis) -> softmax exactly uniform -> out rows = v -> final =
// (x@Wv+bv) @ (sum_h Wo[h*64+d][n]) + bo.  Wq/bq/Wk/bk are mathematically dead.
//
// Prep: WvT[d][k] = Wv[k][d]  (f16)          [64][1024]
//       WosumT[n][d] = sum_h Wo[h*64+d][n]   [1024][64] (f16)
// ---------------------------------------------------------------------------
__global__ __launch_bounds__(256) void prep_kernel(const float* __restrict__ Wv,
                                                   const float* __restrict__ Wo,
                                                   _Float16* __restrict__ WvT,
                                                   _Float16* __restrict__ WosumT) {
    const int t = blockIdx.x * 256 + threadIdx.x;   // 0..65535
    {   // WvT: consecutive t -> consecutive d -> coalesced Wv reads
        const int d = t & 63, k = t >> 6;
        WvT[d * DMODEL + k] = (_Float16)Wv[k * HDIM + d];
    }
    {   // WosumT: consecutive t -> consecutive n -> coalesced Wo reads
        const int n = t & 1023, d = t >> 10;
        float s = 0.f;
        #pragma unroll
        for (int h = 0; h < NHEAD; ++h) s += Wo[(h * HDIM + d) * DMODEL + n];
        WosumT[n * HDIM + d] = (_Float16)s;
    }
}

// ---------------------------------------------------------------------------
// Fused kernel. Block = 16 rows, 4 waves, grid = 1024 (-> 4 blocks/CU,
// 16 waves/CU with launch_bounds(256,4)).
// Phase 1 (K-split): wave w computes partial V[16][64] over K in
//   [w*256,(w+1)*256); X read global->reg (16 float4 in flight), B from
//   L2-resident WvT. Partials -> LDS, ONE barrier, per-lane sum + bv ->
//   f16 A-fragments in registers.
// Phase 2: wave w computes Out cols [w*256,(w+1)*256) in 4 groups of 64;
//   each group's C-tiles bounce through wave-private LDS so global stores
//   are float4 (16/lane instead of 64 scalar stores).
// MFMA 16x16x32 f16: A lane l: A[l&15][(l>>4)*8+j]; B lane l: B[(l>>4)*8+j][l&15];
// C lane l reg j: row (l>>4)*4+j, col l&15.
// ---------------------------------------------------------------------------
#define VP_S 68   // row stride (words): 68%32=4 -> partial-sum reads ~2-way

__global__ __launch_bounds__(256, 4) void mqa_fused(const float* __restrict__ X,
                                                    const float* __restrict__ bv,
                                                    const float* __restrict__ bo,
                                                    const _Float16* __restrict__ WvT,
                                                    const _Float16* __restrict__ WosumT,
                                                    float* __restrict__ Out) {
    __shared__ float Vp[4][16][VP_S];   // 17408 B; reused as per-wave O-stage

    const int tid = threadIdx.x;
    const int l   = tid & 63;
    const int w   = tid >> 6;
    const int lr  = l & 15;
    const int lk  = l >> 4;
    const int m0  = blockIdx.x * 16;
    const int k0  = w * 256;            // wave's K-quarter

    // ---- Phase 1: partial V over K-quarter; X direct global->reg ----
    const float* xp = X + (size_t)(m0 + lr) * DMODEL + k0 + lk * 8;
    f32x4 xb[16];
    #pragma unroll
    for (int s = 0; s < 8; ++s) {
        xb[2 * s]     = *(const f32x4*)(xp + s * 32);
        xb[2 * s + 1] = *(const f32x4*)(xp + s * 32 + 4);
    }
    f32x4 acc[4] = {};
    #pragma unroll
    for (int s = 0; s < 8; ++s) {
        union { _Float16 h[8]; half8 v; } pk;
        const f32x4 x0 = xb[2 * s], x1 = xb[2 * s + 1];
        #pragma unroll
        for (int j = 0; j < 4; ++j) {
            pk.h[j]     = (_Float16)x0[j];
            pk.h[4 + j] = (_Float16)x1[j];
        }
        #pragma unroll
        for (int n4 = 0; n4 < 4; ++n4) {
            const half8 b = *(const half8*)&WvT[(size_t)(n4 * 16 + lr) * DMODEL + k0 + s * 32 + lk * 8];
            acc[n4] = __builtin_amdgcn_mfma_f32_16x16x32_f16(pk.v, b, acc[n4], 0, 0, 0);
        }
    }
    #pragma unroll
    for (int n4 = 0; n4 < 4; ++n4)
        #pragma unroll
        for (int j = 0; j < 4; ++j)
            Vp[w][lk * 4 + j][n4 * 16 + lr] = acc[n4][j];
    __syncthreads();

    // ---- Reduce partials + bv -> f16 A-fragments (V[lr][lk*8..], V[lr][32+lk*8..]) ----
    f32x4 s0a = {}, s0b = {}, s1a = {}, s1b = {};
    #pragma unroll
    for (int p = 0; p < 4; ++p) {
        s0a += *(const f32x4*)&Vp[p][lr][lk * 8];
        s0b += *(const f32x4*)&Vp[p][lr][lk * 8 + 4];
        s1a += *(const f32x4*)&Vp[p][lr][32 + lk * 8];
        s1b += *(const f32x4*)&Vp[p][lr][32 + lk * 8 + 4];
    }
    s0a += *(const f32x4*)&bv[lk * 8];
    s0b += *(const f32x4*)&bv[lk * 8 + 4];
    s1a += *(const f32x4*)&bv[32 + lk * 8];
    s1b += *(const f32x4*)&bv[32 + lk * 8 + 4];
    union { _Float16 h[8]; half8 v; } A0, A1;
    #pragma unroll
    for (int j = 0; j < 4; ++j) {
        A0.h[j] = (_Float16)s0a[j]; A0.h[4 + j] = (_Float16)s0b[j];
        A1.h[j] = (_Float16)s1a[j]; A1.h[4 + j] = (_Float16)s1b[j];
    }
    __syncthreads();   // all Vp reads done -> safe to reuse as O-stage

    // ---- Phase 2: 4 groups of 64 cols, LDS-bounced float4 stores ----
    float* ost = &Vp[w][0][0];          // wave-private 16 x VP_S region
    const int rr = l >> 2;              // store row
    const int cc = (l & 3) * 4;         // store col base within 64-group
    #pragma unroll
    for (int g = 0; g < 4; ++g) {
        const int nbase = w * 256 + g * 64;
        #pragma unroll
        for (int t = 0; t < 4; ++t) {
            const int n0 = nbase + t * 16;
            const half8 b0 = *(const half8*)&WosumT[(size_t)(n0 + lr) * HDIM + lk * 8];
            const half8 b1 = *(const half8*)&WosumT[(size_t)(n0 + lr) * HDIM + 32 + lk * 8];
            f32x4 o = {};
            o = __builtin_amdgcn_mfma_f32_16x16x32_f16(A0.v, b0, o, 0, 0, 0);
            o = __builtin_amdgcn_mfma_f32_16x16x32_f16(A1.v, b1, o, 0, 0, 0);
            #pragma unroll
            for (int j = 0; j < 4; ++j)
                ost[(lk * 4 + j) * VP_S + t * 16 + lr] = o[j];
        }
        #pragma unroll
        for (int j = 0; j < 4; ++j) {
            const f32x4 ov  = *(const f32x4*)&ost[rr * VP_S + cc + j * 16];
            const f32x4 bo4 = *(const f32x4*)&bo[nbase + cc + j * 16];
            *(f32x4*)&Out[(size_t)(m0 + rr) * DMODEL + nbase + cc + j * 16] = ov + bo4;
        }
    }
}

// ---------------------------------------------------------------------------
extern "C" void kernel_launch(void* const* d_in, const int* in_sizes, int n_in,
                              void* d_out, int out_size, void* d_ws, size_t ws_size,
                              hipStream_t stream) {
    const float* x  = (const float*)d_in[0];
    // d_in[1]=Wq, d_in[2]=bq, d_in[3]=Wk, d_in[4]=bk: mathematically dead.
    const float* Wv = (const float*)d_in[5];
    const float* bv = (const float*)d_in[6];
    const float* Wo = (const float*)d_in[7];
    const float* bo = (const float*)d_in[8];

    _Float16* WvT    = (_Float16*)d_ws;                            // 128 KB
    _Float16* WosumT = (_Float16*)((char*)d_ws + 64 * 1024 * 2);   // 128 KB
    float*    out    = (float*)d_out;

    prep_kernel<<<256, 256, 0, stream>>>(Wv, Wo, WvT, WosumT);
    mqa_fused<<<M_TOTAL / 16, 256, 0, stream>>>(x, bv, bo, WvT, WosumT, out);
}